// Round 13
// baseline (93.334 us; speedup 1.0000x reference)
//
#include <hip/hip_runtime.h>
#include <hip/hip_bf16.h>

#define S_LEN 2048
#define DH 64
#define LDPK 72   // K rows: 144B (16B-aligned for b128)
#define LDPV 68   // V^T rows: 136B (8B-aligned for b64)

typedef __attribute__((ext_vector_type(4)))  float f32x4;
typedef __attribute__((ext_vector_type(16))) float f32x16;
typedef __attribute__((ext_vector_type(8)))  short short8v;
typedef __attribute__((ext_vector_type(4)))  unsigned uint4v;
typedef __attribute__((ext_vector_type(2)))  unsigned uint2v;

__device__ __forceinline__ unsigned cvt_pk(float a, float b) {
    unsigned r;
    asm("v_cvt_pk_bf16_f32 %0, %1, %2" : "=v"(r) : "v"(a), "v"(b));
    return r;
}

__global__ __launch_bounds__(512) void fa_fwd_kernel(
    const float* __restrict__ Q, const float* __restrict__ K,
    const float* __restrict__ V, float* __restrict__ O)
{
    const int tid  = threadIdx.x;
    const int lane = tid & 63;
    const int w    = tid >> 6;          // 0..7
    const int bh   = blockIdx.x & 63;   // same-bh blocks 64 apart -> same XCD
    const int p    = blockIdx.x >> 6;   // 0..7

    // split-KV pairing: waves = {row-tile 0..3} x {kv-half 0,1} on ONE q-tile;
    // tiles {15-p, p} processed sequentially -> 17 uniform intervals per block,
    // every wave computes every interval. End-of-tile merge of half-partials.
    const int half = w >> 2;            // 0: low KV half, 1: high half
    const int rt   = w & 3;             // 32-row tile within the q-block

    const size_t base = (size_t)bh * S_LEN * DH;
    const float* Qg = Q + base;
    const float* Kg = K + base;
    const float* Vg = V + base;
    float*       Og = O + base;

    // single-buffered per-half tiles; merge buffer overlays them between tiles
    __shared__ __align__(16) char smem[35840];
    short (*K_lds)[64][LDPK] = (short(*)[64][LDPK])smem;            // [half][kv][d]
    short (*V_lds)[64][LDPV] = (short(*)[64][LDPV])(smem + 18432);  // [half][d][kv]
    float (*Mbuf)[64][34]    = (float(*)[64][34])smem;              // [rt][lane][m,l,o]

    const int q  = lane & 31;           // lane's q-column
    const int hi = lane >> 5;           // 0/1: k-slot half
    // staging decomposition (512 threads cover each 64x64 half-tile once)
    const int kr = tid >> 3;            // K row 0..63
    const int dc = (tid & 7) * 8;       // K col 0,8,...,56
    const int vd = tid & 63;            // V col (d)
    const int vg = tid >> 6;            // V row-group 0..7

    unsigned kpf[2][4], vpf[2][4];      // packed prefetch for both halves

    auto prefetch = [&](int kvbL, int kvbH) {
        #pragma unroll
        for (int hh = 0; hh < 2; ++hh) {
            const int kvb = hh ? kvbH : kvbL;
            const float* kp = Kg + (size_t)(kvb + kr) * DH + dc;
            f32x4 a = *(const f32x4*)kp;
            f32x4 b = *(const f32x4*)(kp + 4);
            kpf[hh][0] = cvt_pk(a[0], a[1]); kpf[hh][1] = cvt_pk(a[2], a[3]);
            kpf[hh][2] = cvt_pk(b[0], b[1]); kpf[hh][3] = cvt_pk(b[2], b[3]);
            #pragma unroll
            for (int i = 0; i < 4; ++i) {
                int kv = vg * 8 + i * 2;
                float x = Vg[(size_t)(kvb + kv) * DH + vd];
                float y = Vg[(size_t)(kvb + kv + 1) * DH + vd];
                vpf[hh][i] = cvt_pk(x, y);
            }
        }
    };

    auto stage = [&]() {
        #pragma unroll
        for (int hh = 0; hh < 2; ++hh) {
            uint4v u = {kpf[hh][0], kpf[hh][1], kpf[hh][2], kpf[hh][3]};
            *(uint4v*)&K_lds[hh][kr][dc] = u;   // ds_write_b128
            #pragma unroll
            for (int i = 0; i < 4; ++i) {
                int kv = vg * 8 + i * 2;
                *(unsigned*)((char*)&V_lds[hh][0][0] + vd * (LDPV * 2) + kv * 2) = vpf[hh][i];
            }
        }
    };

    const float qscale = 0.125f * 1.44269504088896340736f;

    #pragma unroll 1
    for (int t = 0; t < 2; ++t) {
        const int qb = (t == 0) ? (15 - p) : p;   // heavy tile first
        const int nT = qb + 1;                    // intervals for this tile
        const int Hb = nT * 64;                   // high-half stream base
        const int q0 = qb * 128 + rt * 32;        // wave's first q-row

        // ---- Q B-fragments: lane supplies Q[d = ds*16 + hi*8 + j][q0+q] ----
        short8v qfrag[4];
        #pragma unroll
        for (int ds = 0; ds < 4; ++ds) {
            const float* qp = Qg + (size_t)(q0 + q) * DH + ds * 16 + hi * 8;
            f32x4 a = *(const f32x4*)qp;
            f32x4 b = *(const f32x4*)(qp + 4);
            uint4v u;
            u[0] = cvt_pk(a[0] * qscale, a[1] * qscale);
            u[1] = cvt_pk(a[2] * qscale, a[3] * qscale);
            u[2] = cvt_pk(b[0] * qscale, b[1] * qscale);
            u[3] = cvt_pk(b[2] * qscale, b[3] * qscale);
            qfrag[ds] = __builtin_bit_cast(short8v, u);
        }

        f32x16 o_acc[2];
        o_acc[0] = (f32x16)(0.f);
        o_acc[1] = (f32x16)(0.f);
        float m_run = -1e30f, l_run = 0.f;

        prefetch(0, Hb);
        stage();
        __syncthreads();

        #pragma unroll 1
        for (int s = 0; s < nT; ++s) {
            const bool have = (s + 1) < nT;
            if (have) prefetch((s + 1) * 64, Hb + (s + 1) * 64);

            const int kvb_eff = half ? (Hb + s * 64) : (s * 64);
            if (kvb_eff <= q0) {
                const short (*Kc)[LDPK] = K_lds[half];
                const char* Vc = (const char*)&V_lds[half][0][0];

                // ---- swapped QK^T: S^T[kv][q] = K·Q^T, two 32-kv tiles ----
                f32x16 s_acc[2];
                s_acc[0] = (f32x16)(0.f);
                s_acc[1] = (f32x16)(0.f);

                __builtin_amdgcn_s_setprio(1);
                #pragma unroll
                for (int ds = 0; ds < 4; ++ds) {
                    #pragma unroll
                    for (int kt = 0; kt < 2; ++kt) {
                        short8v kf = *(const short8v*)&Kc[kt * 32 + q][ds * 16 + hi * 8];
                        s_acc[kt] = __builtin_amdgcn_mfma_f32_32x32x16_bf16(
                            kf, qfrag[ds], s_acc[kt], 0, 0, 0);
                    }
                }
                __builtin_amdgcn_s_setprio(0);

                // ---- causal mask (diagonal sub-tiles only) ----
                const int qrow = q0 + q;
                if (kvb_eff + 63 > q0) {
                    #pragma unroll
                    for (int kt = 0; kt < 2; ++kt)
                        #pragma unroll
                        for (int r = 0; r < 16; ++r) {
                            int kv = kvb_eff + kt * 32 + (r & 3) + 8 * (r >> 2) + 4 * hi;
                            if (kv > qrow) s_acc[kt][r] = -1e30f;
                        }
                }

                // ---- softmax: in-lane + one shfl_xor(32); defer-max THR=8 ----
                float tl = -1e30f;
                #pragma unroll
                for (int kt = 0; kt < 2; ++kt)
                    #pragma unroll
                    for (int r = 0; r < 16; ++r)
                        tl = fmaxf(tl, s_acc[kt][r]);
                float tmax = fmaxf(tl, __shfl_xor(tl, 32));

                if (!__all(tmax <= m_run + 8.0f)) {
                    float mnew = fmaxf(m_run, tmax);
                    float corr = __builtin_amdgcn_exp2f(m_run - mnew);
                    m_run = mnew;
                    l_run *= corr;
                    #pragma unroll
                    for (int dt = 0; dt < 2; ++dt)
                        #pragma unroll
                        for (int r = 0; r < 16; ++r)
                            o_acc[dt][r] *= corr;
                }

                float rsum = 0.f;
                #pragma unroll
                for (int kt = 0; kt < 2; ++kt)
                    #pragma unroll
                    for (int r = 0; r < 16; ++r) {
                        float pe = __builtin_amdgcn_exp2f(s_acc[kt][r] - m_run);
                        s_acc[kt][r] = pe;
                        rsum += pe;
                    }
                rsum += __shfl_xor(rsum, 32);
                l_run += rsum;

                // ---- pack P; registers land in B-frag k-slot order ----
                unsigned pk_[2][8];
                #pragma unroll
                for (int kt = 0; kt < 2; ++kt)
                    #pragma unroll
                    for (int m = 0; m < 8; ++m)
                        pk_[kt][m] = cvt_pk(s_acc[kt][2 * m], s_acc[kt][2 * m + 1]);

                // ---- PV: O^T += V^T · P ----
                __builtin_amdgcn_s_setprio(1);
                #pragma unroll
                for (int ss = 0; ss < 4; ++ss) {
                    const int kt = ss >> 1, bofs = 4 * (ss & 1);
                    uint4v bu = {pk_[kt][bofs], pk_[kt][bofs + 1],
                                 pk_[kt][bofs + 2], pk_[kt][bofs + 3]};
                    short8v pb = __builtin_bit_cast(short8v, bu);
                    #pragma unroll
                    for (int dt = 0; dt < 2; ++dt) {
                        const char* vrow = Vc + (size_t)(dt * 32 + q) * (LDPV * 2);
                        uint2v lo = *(const uint2v*)(vrow + (16 * ss + 4 * hi) * 2);
                        uint2v h2 = *(const uint2v*)(vrow + (16 * ss + 8 + 4 * hi) * 2);
                        uint4v au = {lo[0], lo[1], h2[0], h2[1]};
                        short8v va = __builtin_bit_cast(short8v, au);
                        o_acc[dt] = __builtin_amdgcn_mfma_f32_32x32x16_bf16(
                            va, pb, o_acc[dt], 0, 0, 0);
                    }
                }
                __builtin_amdgcn_s_setprio(0);
            }

            __syncthreads();            // all computes of tile s done
            if (have) stage();          // overwrite with tile s+1
            __syncthreads();            // staged tile visible
        }

        // ---- merge the two kv-half partials (LDS overlay on dead K/V) ----
        if (half == 1) {
            float* mb = Mbuf[rt][lane];
            mb[0] = m_run;
            mb[1] = l_run;
            #pragma unroll
            for (int d2 = 0; d2 < 2; ++d2)
                #pragma unroll
                for (int r = 0; r < 16; ++r)
                    mb[2 + d2 * 16 + r] = o_acc[d2][r];
        }
        __syncthreads();
        if (half == 0) {
            const float* mb = Mbuf[rt][lane];
            float mB = mb[0], lB = mb[1];
            float mN = fmaxf(m_run, mB);
            float sA = __builtin_amdgcn_exp2f(m_run - mN);   // 0 if A empty (never)
            float sB = __builtin_amdgcn_exp2f(mB - mN);      // 0 if B empty
            float inv = 1.0f / (l_run * sA + lB * sB);
            float* orow = Og + (size_t)(q0 + q) * DH;
            #pragma unroll
            for (int dt = 0; dt < 2; ++dt) {
                #pragma unroll
                for (int g = 0; g < 4; ++g) {
                    f32x4 ov;
                    #pragma unroll
                    for (int i2 = 0; i2 < 4; ++i2)
                        ov[i2] = (o_acc[dt][4 * g + i2] * sA +
                                  mb[2 + dt * 16 + 4 * g + i2] * sB) * inv;
                    *(f32x4*)(orow + dt * 32 + 8 * g + 4 * hi) = ov;
                }
            }
        }
        __syncthreads();                // Mbuf reads done before next tile's stage
    }
}

extern "C" void kernel_launch(void* const* d_in, const int* in_sizes, int n_in,
                              void* d_out, int out_size, void* d_ws, size_t ws_size,
                              hipStream_t stream) {
    const float* q = (const float*)d_in[0];
    const float* k = (const float*)d_in[1];
    const float* v = (const float*)d_in[2];
    float* out = (float*)d_out;
    // 512 blocks x 512 threads: 64 (b,h) x 8 pairs {15-p, p}; split-KV halves
    // inside the block -> 17 uniform intervals, 16 useful waves/CU throughout
    fa_fwd_kernel<<<dim3(512), dim3(512), 0, stream>>>(q, k, v, out);
}